// Round 1
// baseline (940.803 us; speedup 1.0000x reference)
//
#include <hip/hip_runtime.h>
#include <hip/hip_bf16.h>
#include <stdint.h>

// ---------------------------------------------------------------------------
// LoRA attention, fully bf16-MFMA path.
//   y = x@(W + B@A)^T for q,k,v ; flash-attn causal ; o-proj to fp32.
// Shapes: B=4 S=2048 D=2048 H=16 HD=128 R=16. M = B*S = 8192.
// ---------------------------------------------------------------------------

#define L2E 1.4426950408889634f          /* log2(e) */
#define SMSCALE 0.08838834764831845f     /* 1/sqrt(128) */

typedef __attribute__((ext_vector_type(4))) float f32x4;
typedef __attribute__((ext_vector_type(8))) __bf16 bfrag;   // 8 bf16 = 4 VGPR

static __device__ __forceinline__ unsigned short f2bf(float f) {
  union { float f; unsigned u; } v; v.f = f;
  unsigned r = v.u + 0x7FFFu + ((v.u >> 16) & 1u);   // RNE
  return (unsigned short)(r >> 16);
}

static __device__ __forceinline__ void gload16(const void* g, void* l) {
  __builtin_amdgcn_global_load_lds(
      (const __attribute__((address_space(1))) void*)g,
      (__attribute__((address_space(3))) void*)l, 16, 0, 0);
}

// ---------------------------------------------------------------------------
// Weff[n][k] = W[n][k] + sum_r Bm[n][r] * A[r][k]   -> bf16
// one block per n-row; 256 thr * 8 k each.
// ---------------------------------------------------------------------------
__global__ __launch_bounds__(256) void k_fold(const float* __restrict__ W,
                                              const float* __restrict__ A,
                                              const float* __restrict__ Bm,
                                              unsigned short* __restrict__ out) {
  const int n = blockIdx.x;
  const int k0 = threadIdx.x * 8;
  const float* wr = W + (size_t)n * 2048 + k0;
  float acc[8];
#pragma unroll
  for (int j = 0; j < 8; ++j) acc[j] = wr[j];
#pragma unroll 4
  for (int r = 0; r < 16; ++r) {
    float b = Bm[n * 16 + r];
    const float* ar = A + (size_t)r * 2048 + k0;
#pragma unroll
    for (int j = 0; j < 8; ++j) acc[j] = fmaf(b, ar[j], acc[j]);
  }
  unsigned short o[8];
#pragma unroll
  for (int j = 0; j < 8; ++j) o[j] = f2bf(acc[j]);
  *(uint4*)(out + (size_t)n * 2048 + k0) = *(const uint4*)o;
}

// ---------------------------------------------------------------------------
// fp32 -> bf16 convert, 8 elems/thread
// ---------------------------------------------------------------------------
__global__ __launch_bounds__(256) void k_cvt(const float* __restrict__ in,
                                             unsigned short* __restrict__ out) {
  const size_t i = ((size_t)blockIdx.x * 256 + threadIdx.x) * 8;
  unsigned short o[8];
#pragma unroll
  for (int j = 0; j < 8; ++j) o[j] = f2bf(in[i + j]);
  *(uint4*)(out + i) = *(const uint4*)o;
}

// ---------------------------------------------------------------------------
// GEMM  C[m][n] = sum_k A[m][k] * Bw[n][k]   (A,Bw bf16 row-major)
// 128x128 tile, BK=64, 4 waves (2x2), 16x16x32 MFMA.
// LDS linear (global_load_lds), XOR-swizzled content: lds chunk ch of row holds
// global chunk ch^(row&7); reads XOR the same -> conflict-free ds_read_b128.
// MODE 0: write bf16 to [B,H,S,HD] (QKV).  MODE 1: write fp32 flat (final).
// ---------------------------------------------------------------------------
template <int MODE>
__global__ __launch_bounds__(256) void k_gemm(const unsigned short* __restrict__ A,
                                              const unsigned short* __restrict__ Bw,
                                              void* __restrict__ Cout) {
  constexpr int Kd = 2048, Nd = 2048;
  __shared__ unsigned short Asm[128 * 64];   // 16 KB
  __shared__ unsigned short Bsm[128 * 64];   // 16 KB
  const int tid = threadIdx.x, ln = tid & 63, w = tid >> 6;
  const int wm = w >> 1, wn = w & 1, g = ln >> 4, cc = ln & 15;
  const int m0 = blockIdx.y * 128, n0 = blockIdx.x * 128;

  f32x4 acc[4][4] = {};

  for (int kt = 0; kt < Kd; kt += 64) {
#pragma unroll
    for (int i = 0; i < 4; ++i) {
      int cid = i * 256 + tid;           // 0..1023
      int row = cid >> 3, ch = cid & 7;
      int sch = ch ^ (row & 7);          // pre-swizzled source chunk
      gload16(A + (size_t)(m0 + row) * Kd + kt + sch * 8,
              (char*)Asm + cid * 16);
      gload16(Bw + (size_t)(n0 + row) * Kd + kt + sch * 8,
              (char*)Bsm + cid * 16);
    }
    __syncthreads();
#pragma unroll
    for (int s = 0; s < 2; ++s) {
      bfrag af[4], bfr[4];
#pragma unroll
      for (int fm = 0; fm < 4; ++fm) {
        int row = wm * 64 + fm * 16 + cc;
        int o = s * 64 + g * 16;
        af[fm] = *(const bfrag*)((const char*)Asm + row * 128 + (o ^ ((row & 7) << 4)));
      }
#pragma unroll
      for (int fn = 0; fn < 4; ++fn) {
        int row = wn * 64 + fn * 16 + cc;
        int o = s * 64 + g * 16;
        bfr[fn] = *(const bfrag*)((const char*)Bsm + row * 128 + (o ^ ((row & 7) << 4)));
      }
#pragma unroll
      for (int fm = 0; fm < 4; ++fm)
#pragma unroll
        for (int fn = 0; fn < 4; ++fn)
          acc[fm][fn] = __builtin_amdgcn_mfma_f32_16x16x32_bf16(af[fm], bfr[fn],
                                                                acc[fm][fn], 0, 0, 0);
    }
    __syncthreads();
  }

#pragma unroll
  for (int fm = 0; fm < 4; ++fm)
#pragma unroll
    for (int fn = 0; fn < 4; ++fn)
#pragma unroll
      for (int r = 0; r < 4; ++r) {
        int row = m0 + wm * 64 + fm * 16 + g * 4 + r;   // 0..8191  (b*2048+s)
        int col = n0 + wn * 64 + fn * 16 + cc;          // 0..2047  (h*128+hd)
        float v = acc[fm][fn][r];
        if (MODE == 0) {
          int b = row >> 11, s = row & 2047, h = col >> 7, hd = col & 127;
          ((unsigned short*)Cout)[(((size_t)b * 16 + h) * 2048 + s) * 128 + hd] = f2bf(v);
        } else {
          ((float*)Cout)[(size_t)row * Nd + col] = v;
        }
      }
}

// ---------------------------------------------------------------------------
// Flash attention, causal. Q/K/V: [B,H,S,HD] bf16. O: [B,S,D] bf16.
// block: 4 waves, 64 q-rows (16/wave), KV tile 32.
// K LDS [32][136] (padded), V^T LDS [128][40] (padded), P LDS [64][40].
// ---------------------------------------------------------------------------
__global__ __launch_bounds__(256) void k_attn(const unsigned short* __restrict__ Q,
                                              const unsigned short* __restrict__ K,
                                              const unsigned short* __restrict__ V,
                                              unsigned short* __restrict__ O) {
  __shared__ unsigned short Ksm[32 * 136];
  __shared__ unsigned short VT[128 * 40];
  __shared__ unsigned short Psm[64 * 40];
  const int tid = threadIdx.x, ln = tid & 63, w = tid >> 6, g = ln >> 4, cc = ln & 15;
  const int q0 = blockIdx.x * 64, bh = blockIdx.y;
  const size_t base = (size_t)bh * 2048 * 128;
  const unsigned short* Qb = Q + base;
  const unsigned short* Kb = K + base;
  const unsigned short* Vb = V + base;

  // Q fragments (A-operand) held in registers for the whole block
  bfrag qf[4];
  {
    int qrow = q0 + w * 16 + cc;
#pragma unroll
    for (int s = 0; s < 4; ++s)
      qf[s] = *(const bfrag*)(Qb + (size_t)qrow * 128 + s * 32 + g * 8);
  }

  f32x4 acc[8] = {};
  float m_r[4], l_r[4];
#pragma unroll
  for (int r = 0; r < 4; ++r) { m_r[r] = -1e30f; l_r[r] = 0.f; }

  const int kend = q0 + 32;   // last tile start (inclusive)
  for (int k0 = 0; k0 <= kend; k0 += 32) {
    // ---- stage K tile [32][136] (reg-staged, padded: conflict-free reads)
#pragma unroll
    for (int i = 0; i < 2; ++i) {
      int cid = i * 256 + tid;
      int row = cid >> 4, ch = cid & 15;
      uint4 val = *(const uint4*)(Kb + (size_t)(k0 + row) * 128 + ch * 8);
      *(uint4*)((char*)Ksm + row * 272 + ch * 16) = val;
    }
    // ---- stage V^T tile [128][40]
    {
      int nb = tid >> 4, kvp = tid & 15;
      uint4 va = *(const uint4*)(Vb + (size_t)(k0 + kvp * 2) * 128 + nb * 8);
      uint4 vb = *(const uint4*)(Vb + (size_t)(k0 + kvp * 2 + 1) * 128 + nb * 8);
      const unsigned short* pa = (const unsigned short*)&va;
      const unsigned short* pb = (const unsigned short*)&vb;
#pragma unroll
      for (int j = 0; j < 8; ++j) {
        unsigned pk = (unsigned)pa[j] | ((unsigned)pb[j] << 16);
        *(unsigned*)((char*)VT + (size_t)(nb * 8 + j) * 80 + kvp * 4) = pk;
      }
    }
    __syncthreads();

    // ---- S = Q K^T  (per wave: 16q x 32kv)
    f32x4 sf[2] = {};
#pragma unroll
    for (int s = 0; s < 4; ++s)
#pragma unroll
      for (int fn = 0; fn < 2; ++fn) {
        bfrag kf = *(const bfrag*)((const char*)Ksm + (fn * 16 + cc) * 272 + g * 16 + s * 64);
        sf[fn] = __builtin_amdgcn_mfma_f32_16x16x32_bf16(qf[s], kf, sf[fn], 0, 0, 0);
      }

    // ---- scale + causal mask
    float sv[2][4];
#pragma unroll
    for (int fn = 0; fn < 2; ++fn)
#pragma unroll
      for (int r = 0; r < 4; ++r) {
        int kvg = k0 + fn * 16 + cc;
        int qg = q0 + w * 16 + g * 4 + r;
        sv[fn][r] = (kvg > qg) ? -1e30f : sf[fn][r] * SMSCALE;
      }

    // ---- online softmax (rows live in 16-lane groups)
    float mx[4];
#pragma unroll
    for (int r = 0; r < 4; ++r) mx[r] = fmaxf(sv[0][r], sv[1][r]);
#pragma unroll
    for (int off = 8; off >= 1; off >>= 1)
#pragma unroll
      for (int r = 0; r < 4; ++r) mx[r] = fmaxf(mx[r], __shfl_xor(mx[r], off));

    float al[4];
#pragma unroll
    for (int r = 0; r < 4; ++r) {
      float mn = fmaxf(m_r[r], mx[r]);
      al[r] = exp2f((m_r[r] - mn) * L2E);
      m_r[r] = mn;
    }
    float pe[2][4], rs[4] = {0.f, 0.f, 0.f, 0.f};
#pragma unroll
    for (int fn = 0; fn < 2; ++fn)
#pragma unroll
      for (int r = 0; r < 4; ++r) {
        float p = exp2f((sv[fn][r] - m_r[r]) * L2E);
        pe[fn][r] = p;
        rs[r] += p;
      }
#pragma unroll
    for (int off = 8; off >= 1; off >>= 1)
#pragma unroll
      for (int r = 0; r < 4; ++r) rs[r] += __shfl_xor(rs[r], off);
#pragma unroll
    for (int r = 0; r < 4; ++r) l_r[r] = l_r[r] * al[r] + rs[r];
#pragma unroll
    for (int fo = 0; fo < 8; ++fo)
#pragma unroll
      for (int r = 0; r < 4; ++r) acc[fo][r] *= al[r];

    // ---- P -> LDS (wave-private rows; lgkmcnt orders write->read, no barrier)
#pragma unroll
    for (int fn = 0; fn < 2; ++fn)
#pragma unroll
      for (int r = 0; r < 4; ++r)
        *(unsigned short*)((char*)Psm + (size_t)(w * 16 + g * 4 + r) * 80 +
                           (fn * 16 + cc) * 2) = f2bf(pe[fn][r]);
    bfrag pf = *(const bfrag*)((const char*)Psm + (size_t)(w * 16 + cc) * 80 + g * 16);

    // ---- O += P V
#pragma unroll
    for (int fo = 0; fo < 8; ++fo) {
      bfrag vf = *(const bfrag*)((const char*)VT + (size_t)(fo * 16 + cc) * 80 + g * 16);
      acc[fo] = __builtin_amdgcn_mfma_f32_16x16x32_bf16(pf, vf, acc[fo], 0, 0, 0);
    }
    __syncthreads();   // protect K/VT before next stage
  }

  // ---- epilogue: normalize, write [B,S,D] bf16
  float inv[4];
#pragma unroll
  for (int r = 0; r < 4; ++r) inv[r] = 1.f / l_r[r];
  const int b_ = bh >> 4, h_ = bh & 15;
#pragma unroll
  for (int fo = 0; fo < 8; ++fo)
#pragma unroll
    for (int r = 0; r < 4; ++r) {
      int srow = q0 + w * 16 + g * 4 + r;
      int col = fo * 16 + cc;
      O[((size_t)b_ * 2048 + srow) * 2048 + h_ * 128 + col] = f2bf(acc[fo][r] * inv[r]);
    }
}

// ---------------------------------------------------------------------------
extern "C" void kernel_launch(void* const* d_in, const int* in_sizes, int n_in,
                              void* d_out, int out_size, void* d_ws, size_t ws_size,
                              hipStream_t stream) {
  (void)in_sizes; (void)n_in; (void)out_size; (void)ws_size;
  const float* x  = (const float*)d_in[0];
  /* d_in[1] = mask: causal tril, handled analytically */
  const float* Wq = (const float*)d_in[2];
  const float* Aq = (const float*)d_in[3];
  const float* Bq = (const float*)d_in[4];
  const float* Wk = (const float*)d_in[5];
  const float* Ak = (const float*)d_in[6];
  const float* Bk = (const float*)d_in[7];
  const float* Wv = (const float*)d_in[8];
  const float* Av = (const float*)d_in[9];
  const float* Bv = (const float*)d_in[10];
  const float* Wo = (const float*)d_in[11];
  const float* Ao = (const float*)d_in[12];
  const float* Bo = (const float*)d_in[13];

  char* ws = (char*)d_ws;
  unsigned short* xbf = (unsigned short*)ws;                       // 32 MiB
  unsigned short* Wqe = (unsigned short*)(ws + (size_t)33554432);  // 4 x 8 MiB
  unsigned short* Wke = Wqe + 2048 * 2048;
  unsigned short* Wve = Wke + 2048 * 2048;
  unsigned short* Woe = Wve + 2048 * 2048;
  unsigned short* Qb  = (unsigned short*)(ws + (size_t)33554432 + 4u * 8388608u);
  unsigned short* Kb  = Qb + 16777216;                             // 3 x 32 MiB
  unsigned short* Vb  = Kb + 16777216;
  unsigned short* AO  = xbf;   // reuse x_bf16 buffer for attention output

  k_fold<<<2048, 256, 0, stream>>>(Wq, Aq, Bq, Wqe);
  k_fold<<<2048, 256, 0, stream>>>(Wk, Ak, Bk, Wke);
  k_fold<<<2048, 256, 0, stream>>>(Wv, Av, Bv, Wve);
  k_fold<<<2048, 256, 0, stream>>>(Wo, Ao, Bo, Woe);
  k_cvt<<<8192, 256, 0, stream>>>(x, xbf);

  dim3 gg(16, 64);   // N/128, M/128
  k_gemm<0><<<gg, 256, 0, stream>>>(xbf, Wqe, Qb);
  k_gemm<0><<<gg, 256, 0, stream>>>(xbf, Wke, Kb);
  k_gemm<0><<<gg, 256, 0, stream>>>(xbf, Wve, Vb);

  dim3 ga(32, 64);   // S/64 q-blocks, B*H
  k_attn<<<ga, 256, 0, stream>>>(Qb, Kb, Vb, AO);

  k_gemm<1><<<gg, 256, 0, stream>>>(AO, Woe, d_out);
}

// Round 3
// 505.203 us; speedup vs baseline: 1.8622x; 1.8622x over previous
//
#include <hip/hip_runtime.h>
#include <hip/hip_bf16.h>
#include <stdint.h>

// ---------------------------------------------------------------------------
// LoRA attention, fully bf16-MFMA path.
//   y = x@(W + B@A)^T for q,k,v ; flash-attn causal (swapped-operand) ;
//   o-proj to fp32.
// Shapes: B=4 S=2048 D=2048 H=16 HD=128 R=16. M = B*S = 8192.
// ---------------------------------------------------------------------------

#define L2E 1.4426950408889634f
#define SMSCALE 0.08838834764831845f
#define NEGBIG -3.0e38f

typedef __attribute__((ext_vector_type(4))) float f32x4;
typedef __attribute__((ext_vector_type(16))) float f32x16;
typedef __attribute__((ext_vector_type(8))) __bf16 bfrag;   // 8 bf16 = 4 VGPR

#if __has_builtin(__builtin_amdgcn_exp2f)
#define EXP2 __builtin_amdgcn_exp2f
#else
#define EXP2 exp2f
#endif

// Explicit LDS-DMA drain: do NOT rely on the implicit vmcnt(0) at s_barrier —
// k_attn's epilogue reuses the prefetch LDS region, so a late-landing
// global_load_lds would stomp it (race seen as replay-only divergence).
#define DRAIN_VM                                      \
  do {                                                \
    asm volatile("s_waitcnt vmcnt(0)" ::: "memory");  \
    __builtin_amdgcn_sched_barrier(0);                \
  } while (0)

static __device__ __forceinline__ unsigned short f2bf(float f) {
  union { float f; unsigned u; } v; v.f = f;
  unsigned r = v.u + 0x7FFFu + ((v.u >> 16) & 1u);   // RNE
  return (unsigned short)(r >> 16);
}

static __device__ __forceinline__ void gload16(const void* g, void* l) {
  __builtin_amdgcn_global_load_lds(
      (const __attribute__((address_space(1))) void*)g,
      (__attribute__((address_space(3))) void*)l, 16, 0, 0);
}

// ---------------------------------------------------------------------------
// Weff[n][k] = W[n][k] + sum_r Bm[n][r] * A[r][k]   -> bf16
// ---------------------------------------------------------------------------
__global__ __launch_bounds__(256) void k_fold(const float* __restrict__ W,
                                              const float* __restrict__ A,
                                              const float* __restrict__ Bm,
                                              unsigned short* __restrict__ out) {
  const int n = blockIdx.x;
  const int k0 = threadIdx.x * 8;
  const float* wr = W + (size_t)n * 2048 + k0;
  float acc[8];
#pragma unroll
  for (int j = 0; j < 8; ++j) acc[j] = wr[j];
#pragma unroll 4
  for (int r = 0; r < 16; ++r) {
    float b = Bm[n * 16 + r];
    const float* ar = A + (size_t)r * 2048 + k0;
#pragma unroll
    for (int j = 0; j < 8; ++j) acc[j] = fmaf(b, ar[j], acc[j]);
  }
  unsigned short o[8];
#pragma unroll
  for (int j = 0; j < 8; ++j) o[j] = f2bf(acc[j]);
  *(uint4*)(out + (size_t)n * 2048 + k0) = *(const uint4*)o;
}

// ---------------------------------------------------------------------------
__global__ __launch_bounds__(256) void k_cvt(const float* __restrict__ in,
                                             unsigned short* __restrict__ out) {
  const size_t i = ((size_t)blockIdx.x * 256 + threadIdx.x) * 8;
  unsigned short o[8];
#pragma unroll
  for (int j = 0; j < 8; ++j) o[j] = f2bf(in[i + j]);
  *(uint4*)(out + i) = *(const uint4*)o;
}

// ---------------------------------------------------------------------------
// GEMM  C[m][n] = sum_k A[m][k] * Bw[n][k]   (A,Bw bf16 row-major)
// 128x128 tile, BK=64, 4 waves, 16x16x32 MFMA, XOR-swizzled LDS.
// MODE 0: bf16 -> [B,H,S,HD], scaled (Q/K).  MODE 1: fp32 flat (final).
// MODE 2: bf16 -> [B,H,HD,S]  (V transposed for attention A-operand).
// ---------------------------------------------------------------------------
template <int MODE>
__global__ __launch_bounds__(256) void k_gemm(const unsigned short* __restrict__ A,
                                              const unsigned short* __restrict__ Bw,
                                              void* __restrict__ Cout, float scale) {
  constexpr int Kd = 2048, Nd = 2048;
  __shared__ unsigned short Asm[128 * 64];
  __shared__ unsigned short Bsm[128 * 64];
  const int tid = threadIdx.x, ln = tid & 63, w = tid >> 6;
  const int wm = w >> 1, wn = w & 1, g = ln >> 4, cc = ln & 15;
  const int m0 = blockIdx.y * 128, n0 = blockIdx.x * 128;

  f32x4 acc[4][4] = {};

  for (int kt = 0; kt < Kd; kt += 64) {
#pragma unroll
    for (int i = 0; i < 4; ++i) {
      int cid = i * 256 + tid;
      int row = cid >> 3, ch = cid & 7;
      int sch = ch ^ (row & 7);
      gload16(A + (size_t)(m0 + row) * Kd + kt + sch * 8,
              (char*)Asm + cid * 16);
      gload16(Bw + (size_t)(n0 + row) * Kd + kt + sch * 8,
              (char*)Bsm + cid * 16);
    }
    __syncthreads();
#pragma unroll
    for (int s = 0; s < 2; ++s) {
      bfrag af[4], bfr[4];
#pragma unroll
      for (int fm = 0; fm < 4; ++fm) {
        int row = wm * 64 + fm * 16 + cc;
        int o = s * 64 + g * 16;
        af[fm] = *(const bfrag*)((const char*)Asm + row * 128 + (o ^ ((row & 7) << 4)));
      }
#pragma unroll
      for (int fn = 0; fn < 4; ++fn) {
        int row = wn * 64 + fn * 16 + cc;
        int o = s * 64 + g * 16;
        bfr[fn] = *(const bfrag*)((const char*)Bsm + row * 128 + (o ^ ((row & 7) << 4)));
      }
#pragma unroll
      for (int fm = 0; fm < 4; ++fm)
#pragma unroll
        for (int fn = 0; fn < 4; ++fn)
          acc[fm][fn] = __builtin_amdgcn_mfma_f32_16x16x32_bf16(af[fm], bfr[fn],
                                                                acc[fm][fn], 0, 0, 0);
    }
    __syncthreads();
  }

#pragma unroll
  for (int fm = 0; fm < 4; ++fm)
#pragma unroll
    for (int fn = 0; fn < 4; ++fn)
#pragma unroll
      for (int r = 0; r < 4; ++r) {
        int row = m0 + wm * 64 + fm * 16 + g * 4 + r;   // m = b*2048+s
        int col = n0 + wn * 64 + fn * 16 + cc;          // n = h*128+hd
        float v = acc[fm][fn][r];
        if (MODE == 0) {
          int b = row >> 11, s = row & 2047, h = col >> 7, hd = col & 127;
          ((unsigned short*)Cout)[(((size_t)b * 16 + h) * 2048 + s) * 128 + hd] =
              f2bf(v * scale);
        } else if (MODE == 2) {
          int b = row >> 11, s = row & 2047, h = col >> 7, hd = col & 127;
          ((unsigned short*)Cout)[(((size_t)b * 16 + h) * 128 + hd) * 2048 + s] =
              f2bf(v);
        } else {
          ((float*)Cout)[(size_t)row * Nd + col] = v;
        }
      }
}

// ---------------------------------------------------------------------------
// Flash attention, causal, swapped-operand (m214-style), 32x32x16 MFMA.
// Q,K: [B,H,S,HD] bf16 (Q prescaled by SMSCALE*L2E). Vt: [B,H,HD,S] bf16.
// O: [B,S,D] bf16. 8 waves x 32 q-rows, KVBLK=64, dbuf LDS, XOR swizzle.
// Lane owns q = qw0 + (lane&31); S^T/O^T keep q in the MFMA column.
// ---------------------------------------------------------------------------
__global__ __launch_bounds__(512) void k_attn(const unsigned short* __restrict__ Q,
                                              const unsigned short* __restrict__ K,
                                              const unsigned short* __restrict__ Vt,
                                              unsigned short* __restrict__ O) {
  __shared__ __align__(16) unsigned char lds[65536];   // 2 x (16K K + 16K V)
  const int tid = threadIdx.x;
  const int ln = tid & 63, w = tid >> 6;
  const int l31 = ln & 31, hi = ln >> 5;
  const int rk = l31 & 15;
  const int bx = blockIdx.x;
  const int qb = 7 - (bx >> 6);          // heavy-first dispatch order
  const int bh = bx & 63;
  const int q0 = qb * 256;
  const size_t base = (size_t)bh * 2048 * 128;
  const unsigned short* Qb = Q + base;
  const unsigned short* Kb = K + base;
  const unsigned short* Vb = Vt + base;

  const int qw0 = q0 + w * 32;
  const int qg = qw0 + l31;

  // Q fragments (B-operand: col q = lane&31, d = dc*16 + hi*8 + j)
  bfrag qf[8];
#pragma unroll
  for (int dc = 0; dc < 8; ++dc)
    qf[dc] = *(const bfrag*)(Qb + (size_t)qg * 128 + dc * 16 + hi * 8);

  f32x16 o[4] = {};            // O^T acc: [d = db*32 + pat(r,hi)][q = lane&31]
  float m_r = NEGBIG, l_r = 0.f;

  const int nt = q0 / 64 + 4;

  // stage K tile [64][16ch] and V^T tile [64row'][16ch], XOR-16 swizzled
  // (LDS position p of row holds global chunk p ^ (row&15))
  auto stage = [&](int buf, int k0) {
    unsigned char* Kt = lds + buf * 32768;
    unsigned char* Vl = Kt + 16384;
#pragma unroll
    for (int i = 0; i < 2; ++i) {
      int cid = i * 512 + tid;
      int row = cid >> 4, p = cid & 15, sc = p ^ (row & 15);
      gload16(Kb + (size_t)(k0 + row) * 128 + sc * 8, Kt + cid * 16);
    }
#pragma unroll
    for (int i = 0; i < 2; ++i) {
      int cid = i * 512 + tid;
      int row = cid >> 4, p = cid & 15, sc = p ^ (row & 15);
      int d = (sc >> 3) * 64 + row;
      gload16(Vb + (size_t)d * 2048 + k0 + (sc & 7) * 8, Vl + cid * 16);
    }
  };

  stage(0, 0);
  DRAIN_VM;
  __syncthreads();
  int buf = 0;

  for (int t = 0; t < nt; ++t) {
    const int k0 = t * 64;
    if (t + 1 < nt) stage(buf ^ 1, k0 + 64);   // prefetch under compute

    if (k0 <= qw0 + 31) {                      // wave-uniform causal skip
      const unsigned char* Kt = lds + buf * 32768;
      const unsigned char* Vl = Kt + 16384;

      // ---- S^T[kb][16] = K * Q^T  (k rows, q cols)
      f32x16 s0 = {}, s1 = {};
#pragma unroll
      for (int dc = 0; dc < 8; ++dc) {
        int c = dc * 2 + hi;
        bfrag ka = *(const bfrag*)(Kt + (size_t)l31 * 256 + ((c ^ rk) << 4));
        bfrag kb2 = *(const bfrag*)(Kt + (size_t)(32 + l31) * 256 + ((c ^ rk) << 4));
        s0 = __builtin_amdgcn_mfma_f32_32x32x16_bf16(ka, qf[dc], s0, 0, 0, 0);
        s1 = __builtin_amdgcn_mfma_f32_32x32x16_bf16(kb2, qf[dc], s1, 0, 0, 0);
      }

      // ---- causal mask (diagonal tiles only); k-row of reg r:
      //      kloc = (r&3) + 8*(r>>2) + 4*hi  (+32 for s1)
      if (k0 + 63 > qw0) {
#pragma unroll
        for (int r = 0; r < 16; ++r) {
          int ko = (r & 3) + 8 * (r >> 2) + 4 * hi;
          if (k0 + ko > qg) s0[r] = NEGBIG;
          if (k0 + 32 + ko > qg) s1[r] = NEGBIG;
        }
      }

      // ---- row max (q is lane-local; only lane^32 holds the other half)
      float pmax = s0[0];
#pragma unroll
      for (int r = 1; r < 16; ++r) pmax = fmaxf(pmax, s0[r]);
#pragma unroll
      for (int r = 0; r < 16; ++r) pmax = fmaxf(pmax, s1[r]);
      pmax = fmaxf(pmax, __shfl_xor(pmax, 32));

      // ---- defer-max rescale (T13), log2 domain (Q prescaled by L2E)
      if (!__all(pmax - m_r <= 12.f)) {
        float mn = fmaxf(m_r, pmax);
        float al = EXP2(m_r - mn);
        l_r *= al;
#pragma unroll
        for (int db = 0; db < 4; ++db)
#pragma unroll
          for (int r = 0; r < 16; ++r) o[db][r] *= al;
        m_r = mn;
      }

      // ---- exp2 + pack to bf16 quads (quad s of kb holds k = kb*32+8s+4hi+t)
      unsigned qd0[8], qd1[8];
      float rs = 0.f;
#pragma unroll
      for (int s = 0; s < 4; ++s) {
        float p0 = EXP2(s0[4 * s + 0] - m_r), p1 = EXP2(s0[4 * s + 1] - m_r);
        float p2 = EXP2(s0[4 * s + 2] - m_r), p3 = EXP2(s0[4 * s + 3] - m_r);
        rs += (p0 + p1) + (p2 + p3);
        qd0[2 * s] = (unsigned)f2bf(p0) | ((unsigned)f2bf(p1) << 16);
        qd0[2 * s + 1] = (unsigned)f2bf(p2) | ((unsigned)f2bf(p3) << 16);
      }
#pragma unroll
      for (int s = 0; s < 4; ++s) {
        float p0 = EXP2(s1[4 * s + 0] - m_r), p1 = EXP2(s1[4 * s + 1] - m_r);
        float p2 = EXP2(s1[4 * s + 2] - m_r), p3 = EXP2(s1[4 * s + 3] - m_r);
        rs += (p0 + p1) + (p2 + p3);
        qd1[2 * s] = (unsigned)f2bf(p0) | ((unsigned)f2bf(p1) << 16);
        qd1[2 * s + 1] = (unsigned)f2bf(p2) | ((unsigned)f2bf(p3) << 16);
      }
      rs += __shfl_xor(rs, 32);
      l_r += rs;

      // ---- O^T += V^T * P^T ; B-frag[kc] j<4 from hi_src=0, j>=4 from
      //      hi_src=1, quad index 2*(kc&1)+hi -> single lane^32 exchange
#define PVSTEP(QD, B0, KC)                                                    \
  do {                                                                        \
    unsigned e0 = QD[B0], e1 = QD[B0 + 1], x0 = QD[B0 + 2], x1 = QD[B0 + 3];  \
    unsigned kp0 = hi ? x0 : e0, kp1 = hi ? x1 : e1;                          \
    unsigned sd0 = hi ? e0 : x0, sd1 = hi ? e1 : x1;                          \
    unsigned rc0 = (unsigned)__shfl_xor((int)sd0, 32);                        \
    unsigned rc1 = (unsigned)__shfl_xor((int)sd1, 32);                        \
    unsigned pw[4];                                                           \
    pw[0] = hi ? rc0 : kp0; pw[1] = hi ? rc1 : kp1;                           \
    pw[2] = hi ? kp0 : rc0; pw[3] = hi ? kp1 : rc1;                           \
    bfrag pf = *(bfrag*)pw;                                                   \
    _Pragma("unroll")                                                         \
    for (int db = 0; db < 4; ++db) {                                          \
      int c = (db >> 1) * 8 + KC * 2 + hi;                                    \
      bfrag vf = *(const bfrag*)(Vl + (size_t)((db & 1) * 32 + l31) * 256 +   \
                                 ((c ^ rk) << 4));                            \
      o[db] = __builtin_amdgcn_mfma_f32_32x32x16_bf16(vf, pf, o[db], 0, 0, 0);\
    }                                                                         \
  } while (0)

      PVSTEP(qd0, 0, 0);
      PVSTEP(qd0, 4, 1);
      PVSTEP(qd1, 0, 2);
      PVSTEP(qd1, 4, 3);
#undef PVSTEP
    }
    DRAIN_VM;
    __syncthreads();
    buf ^= 1;
  }

  // ---- epilogue: normalize, transpose O^T -> O via LDS (2 phases, 4 waves)
  float invl = 1.0f / l_r;
  const int b_ = bh >> 4, h_ = bh & 15;
#pragma unroll
  for (int ph = 0; ph < 2; ++ph) {
    if ((w >> 2) == ph) {
      unsigned char* ep = lds + (w & 3) * 8704;   // [32 q][136 d] bf16
#pragma unroll
      for (int db = 0; db < 4; ++db)
#pragma unroll
        for (int s = 0; s < 4; ++s) {
          int d0 = db * 32 + 8 * s + 4 * hi;
          float v0 = o[db][4 * s] * invl, v1 = o[db][4 * s + 1] * invl;
          float v2 = o[db][4 * s + 2] * invl, v3 = o[db][4 * s + 3] * invl;
          uint2 pw;
          pw.x = (unsigned)f2bf(v0) | ((unsigned)f2bf(v1) << 16);
          pw.y = (unsigned)f2bf(v2) | ((unsigned)f2bf(v3) << 16);
          *(uint2*)(ep + l31 * 272 + d0 * 2) = pw;
        }
    }
    __syncthreads();
    if ((w >> 2) == ph) {
      const unsigned char* ep = lds + (w & 3) * 8704;
#pragma unroll
      for (int i = 0; i < 8; ++i) {
        int cid = i * 64 + ln;
        int q = cid >> 4, ch = cid & 15;
        uint4 val = *(const uint4*)(ep + q * 272 + ch * 16);
        *(uint4*)(O + ((size_t)(b_ * 2048 + q0 + w * 32 + q)) * 2048 +
                  h_ * 128 + ch * 8) = val;
      }
    }
    __syncthreads();
  }
}

// ---------------------------------------------------------------------------
extern "C" void kernel_launch(void* const* d_in, const int* in_sizes, int n_in,
                              void* d_out, int out_size, void* d_ws, size_t ws_size,
                              hipStream_t stream) {
  (void)in_sizes; (void)n_in; (void)out_size; (void)ws_size;
  const float* x  = (const float*)d_in[0];
  /* d_in[1] = mask: causal tril, handled analytically */
  const float* Wq = (const float*)d_in[2];
  const float* Aq = (const float*)d_in[3];
  const float* Bq = (const float*)d_in[4];
  const float* Wk = (const float*)d_in[5];
  const float* Ak = (const float*)d_in[6];
  const float* Bk = (const float*)d_in[7];
  const float* Wv = (const float*)d_in[8];
  const float* Av = (const float*)d_in[9];
  const float* Bv = (const float*)d_in[10];
  const float* Wo = (const float*)d_in[11];
  const float* Ao = (const float*)d_in[12];
  const float* Bo = (const float*)d_in[13];

  char* ws = (char*)d_ws;
  unsigned short* xbf = (unsigned short*)ws;                       // 32 MiB
  unsigned short* Wqe = (unsigned short*)(ws + (size_t)33554432);  // 4 x 8 MiB
  unsigned short* Wke = Wqe + 2048 * 2048;
  unsigned short* Wve = Wke + 2048 * 2048;
  unsigned short* Woe = Wve + 2048 * 2048;
  unsigned short* Qb  = (unsigned short*)(ws + (size_t)33554432 + 4u * 8388608u);
  unsigned short* Kb  = Qb + 16777216;                             // 3 x 32 MiB
  unsigned short* Vtb = Kb + 16777216;                             // V^T
  unsigned short* AO  = xbf;   // reuse x_bf16 buffer for attention output

  k_fold<<<2048, 256, 0, stream>>>(Wq, Aq, Bq, Wqe);
  k_fold<<<2048, 256, 0, stream>>>(Wk, Ak, Bk, Wke);
  k_fold<<<2048, 256, 0, stream>>>(Wv, Av, Bv, Wve);
  k_fold<<<2048, 256, 0, stream>>>(Wo, Ao, Bo, Woe);
  k_cvt<<<8192, 256, 0, stream>>>(x, xbf);

  dim3 gg(16, 64);   // N/128, M/128
  k_gemm<0><<<gg, 256, 0, stream>>>(xbf, Wqe, Qb, SMSCALE * L2E);  // Q prescaled
  k_gemm<0><<<gg, 256, 0, stream>>>(xbf, Wke, Kb, 1.0f);
  k_gemm<2><<<gg, 256, 0, stream>>>(xbf, Wve, Vtb, 1.0f);          // V transposed

  k_attn<<<512, 512, 0, stream>>>(Qb, Kb, Vtb, AO);

  k_gemm<1><<<gg, 256, 0, stream>>>(AO, Woe, d_out, 1.0f);
}

// Round 4
// 422.269 us; speedup vs baseline: 2.2280x; 1.1964x over previous
//
#include <hip/hip_runtime.h>
#include <hip/hip_bf16.h>
#include <stdint.h>

// ---------------------------------------------------------------------------
// LoRA attention, fully bf16-MFMA path.
//   y = x@(W + B@A)^T for q,k,v ; flash-attn causal (swapped-operand) ;
//   o-proj to fp32.
// Shapes: B=4 S=2048 D=2048 H=16 HD=128 R=16. M = B*S = 8192.
// ---------------------------------------------------------------------------

#define L2E 1.4426950408889634f
#define SMSCALE 0.08838834764831845f
#define NEGBIG -3.0e38f

typedef __attribute__((ext_vector_type(4))) float f32x4;
typedef __attribute__((ext_vector_type(16))) float f32x16;
typedef __attribute__((ext_vector_type(8))) __bf16 bfrag;   // 8 bf16 = 4 VGPR

#if __has_builtin(__builtin_amdgcn_exp2f)
#define EXP2 __builtin_amdgcn_exp2f
#else
#define EXP2 exp2f
#endif

// Explicit LDS-DMA drain (k_attn): the epilogue reuses the prefetch LDS
// region, so a late-landing global_load_lds would stomp it.
#define DRAIN_VM                                      \
  do {                                                \
    asm volatile("s_waitcnt vmcnt(0)" ::: "memory");  \
    __builtin_amdgcn_sched_barrier(0);                \
  } while (0)

static __device__ __forceinline__ unsigned short f2bf(float f) {
  union { float f; unsigned u; } v; v.f = f;
  unsigned r = v.u + 0x7FFFu + ((v.u >> 16) & 1u);   // RNE
  return (unsigned short)(r >> 16);
}

static __device__ __forceinline__ void gload16(const void* g, void* l) {
  __builtin_amdgcn_global_load_lds(
      (const __attribute__((address_space(1))) void*)g,
      (__attribute__((address_space(3))) void*)l, 16, 0, 0);
}

// ---------------------------------------------------------------------------
// Weff[n][k] = W[n][k] + sum_r Bm[n][r] * A[r][k]   -> bf16
// ---------------------------------------------------------------------------
__global__ __launch_bounds__(256) void k_fold(const float* __restrict__ W,
                                              const float* __restrict__ A,
                                              const float* __restrict__ Bm,
                                              unsigned short* __restrict__ out) {
  const int n = blockIdx.x;
  const int k0 = threadIdx.x * 8;
  const float* wr = W + (size_t)n * 2048 + k0;
  float acc[8];
#pragma unroll
  for (int j = 0; j < 8; ++j) acc[j] = wr[j];
#pragma unroll 4
  for (int r = 0; r < 16; ++r) {
    float b = Bm[n * 16 + r];
    const float* ar = A + (size_t)r * 2048 + k0;
#pragma unroll
    for (int j = 0; j < 8; ++j) acc[j] = fmaf(b, ar[j], acc[j]);
  }
  unsigned short o[8];
#pragma unroll
  for (int j = 0; j < 8; ++j) o[j] = f2bf(acc[j]);
  *(uint4*)(out + (size_t)n * 2048 + k0) = *(const uint4*)o;
}

// ---------------------------------------------------------------------------
__global__ __launch_bounds__(256) void k_cvt(const float* __restrict__ in,
                                             unsigned short* __restrict__ out) {
  const size_t i = ((size_t)blockIdx.x * 256 + threadIdx.x) * 8;
  unsigned short o[8];
#pragma unroll
  for (int j = 0; j < 8; ++j) o[j] = f2bf(in[i + j]);
  *(uint4*)(out + i) = *(const uint4*)o;
}

// ---------------------------------------------------------------------------
// GEMM2: 256x256 tile, BK=64, 8 waves (2Mx4N), phase-interleaved counted-vmcnt
// pipeline (T2+T3+T4+T5), 128 KiB LDS.
//   C[m][n] = sum_k A[m][k] * Bw[n][k]
// LDS per operand: [2 buf][2 K-half][256 rows][32 k] bf16; within a row (64B,
// 4 chunks of 16B) chunk c sits at position c ^ ((row>>1)&3)  (2-way banks).
// Phases per K-tile (buf = T&1; stages write buf^1 = tile T+1):
//   p0: read A[ks=0](8xb128)+B[ks=0,n01](2) | stage A(T+1,h0) | bar | 16 MFMA
//   p1: read B[ks=0,n23](2)                 | stage B(T+1,h0) | vmcnt(4) bar | 16 MFMA
//   p2: read A[ks=1](8)+B[ks=1,n01](2)      | stage A(T+1,h1) | bar | 16 MFMA
//   p3: read B[ks=1,n23](2)                 | stage B(T+1,h1) | vmcnt(4) bar | 16 MFMA
// Ledger: T.p0 reads h0 staged at (T-1).p0/p1, retired by vmcnt(4)@(T-1).p3
// (outstanding there = (T-1).p0..p3 = 8 loads -> oldest 4 land). T.p2 reads h1
// staged at (T-1).p2/p3, retired by vmcnt(4)@T.p1. Stages overwrite only the
// buffer dead since (T-1).p3 (>=1 barrier). Loads never drain to 0.
// MODE 0: bf16 -> [B,H,S,HD] scaled. MODE 1: fp32 flat. MODE 2: bf16 [B,H,HD,S].
// ---------------------------------------------------------------------------
template <int MODE>
__global__ __launch_bounds__(512, 2) void k_gemm2(const unsigned short* __restrict__ A,
                                                  const unsigned short* __restrict__ Bw,
                                                  void* __restrict__ Cout, float scale) {
  __shared__ __align__(16) unsigned char lds[131072];
  unsigned char* Al = lds;            // A: 2 x 32 KB
  unsigned char* Bl = lds + 65536;    // B: 2 x 32 KB
  const int tid = threadIdx.x, ln = tid & 63;
  const int w = tid >> 6, g = ln >> 4, cc = ln & 15;
  const int wm = w >> 2, wn = w & 3;
  const int bid = blockIdx.x;
  const int wg = (bid & 7) * 32 + (bid >> 3);   // bijective XCD swizzle (256 wgs)
  const int m0 = (wg >> 3) * 256, n0 = (wg & 7) * 256;

  // per-thread staging constants: cid = i*512+tid -> row, chunk pos
  int soff[2], sdst[2];
#pragma unroll
  for (int i = 0; i < 2; ++i) {
    int cid = i * 512 + tid, r = cid >> 2, p = cid & 3;
    int sc = p ^ ((r >> 1) & 3);
    soff[i] = r * 2048 + sc * 8;      // + base_row*2048 + kt + h*32
    sdst[i] = cid * 16;               // + buf*32768 + h*16384
  }
  // per-thread ds_read offsets
  int aro[8], bro[4];
#pragma unroll
  for (int fm = 0; fm < 8; ++fm) {
    int r = wm * 128 + fm * 16 + cc;
    aro[fm] = r * 64 + ((g ^ ((r >> 1) & 3)) << 4);
  }
#pragma unroll
  for (int fn = 0; fn < 4; ++fn) {
    int r = wn * 64 + fn * 16 + cc;
    bro[fn] = r * 64 + ((g ^ ((r >> 1) & 3)) << 4);
  }

#define STAGE_A(b, kt, h)                                                   \
  do {                                                                      \
    _Pragma("unroll")                                                       \
    for (int i = 0; i < 2; ++i)                                             \
      gload16(A + (size_t)m0 * 2048 + soff[i] + (kt) + (h) * 32,            \
              Al + (b) * 32768 + (h) * 16384 + sdst[i]);                    \
  } while (0)
#define STAGE_B(b, kt, h)                                                   \
  do {                                                                      \
    _Pragma("unroll")                                                       \
    for (int i = 0; i < 2; ++i)                                             \
      gload16(Bw + (size_t)n0 * 2048 + soff[i] + (kt) + (h) * 32,           \
              Bl + (b) * 32768 + (h) * 16384 + sdst[i]);                    \
  } while (0)

  f32x4 acc[8][4] = {};

  // prologue: stage tile 0 fully; land h0 (oldest 4 loads), keep h1 in flight
  STAGE_A(0, 0, 0); STAGE_B(0, 0, 0); STAGE_A(0, 0, 1); STAGE_B(0, 0, 1);
  asm volatile("s_waitcnt vmcnt(4)" ::: "memory");
  __builtin_amdgcn_s_barrier();
  __builtin_amdgcn_sched_barrier(0);

  for (int T = 0; T < 32; ++T) {
    const int buf = T & 1;
    const unsigned char* Ab = Al + buf * 32768;
    const unsigned char* Bb = Bl + buf * 32768;
    const int ktn = (T + 1) * 64;
    const bool pf = (T + 1 < 32);
#pragma unroll
    for (int ks = 0; ks < 2; ++ks) {
      bfrag af[8], bf[4];
      // ---- phase ks.0 : A frags + B n-frags 0,1
#pragma unroll
      for (int fm = 0; fm < 8; ++fm)
        af[fm] = *(const bfrag*)(Ab + ks * 16384 + aro[fm]);
#pragma unroll
      for (int j = 0; j < 2; ++j)
        bf[j] = *(const bfrag*)(Bb + ks * 16384 + bro[j]);
      if (pf) STAGE_A(buf ^ 1, ktn, ks);
      __builtin_amdgcn_sched_barrier(0);
      __builtin_amdgcn_s_barrier();
      __builtin_amdgcn_sched_barrier(0);
      __builtin_amdgcn_s_setprio(1);
#pragma unroll
      for (int fm = 0; fm < 8; ++fm)
#pragma unroll
        for (int j = 0; j < 2; ++j)
          acc[fm][j] = __builtin_amdgcn_mfma_f32_16x16x32_bf16(af[fm], bf[j],
                                                               acc[fm][j], 0, 0, 0);
      __builtin_amdgcn_s_setprio(0);
      __builtin_amdgcn_sched_barrier(0);
      // ---- phase ks.1 : B n-frags 2,3
#pragma unroll
      for (int j = 0; j < 2; ++j)
        bf[2 + j] = *(const bfrag*)(Bb + ks * 16384 + bro[2 + j]);
      if (pf) STAGE_B(buf ^ 1, ktn, ks);
      __builtin_amdgcn_sched_barrier(0);
      asm volatile("s_waitcnt vmcnt(4)" ::: "memory");
      __builtin_amdgcn_s_barrier();
      __builtin_amdgcn_sched_barrier(0);
      __builtin_amdgcn_s_setprio(1);
#pragma unroll
      for (int fm = 0; fm < 8; ++fm)
#pragma unroll
        for (int j = 0; j < 2; ++j)
          acc[fm][2 + j] = __builtin_amdgcn_mfma_f32_16x16x32_bf16(af[fm], bf[2 + j],
                                                                   acc[fm][2 + j], 0, 0, 0);
      __builtin_amdgcn_s_setprio(0);
      __builtin_amdgcn_sched_barrier(0);
    }
  }
#undef STAGE_A
#undef STAGE_B

  // ---- epilogue: direct global stores from registers (no LDS use)
#pragma unroll
  for (int fm = 0; fm < 8; ++fm)
#pragma unroll
    for (int fn = 0; fn < 4; ++fn)
#pragma unroll
      for (int r = 0; r < 4; ++r) {
        int row = m0 + wm * 128 + fm * 16 + g * 4 + r;   // m = b*2048+s
        int col = n0 + wn * 64 + fn * 16 + cc;           // n = h*128+hd
        float v = acc[fm][fn][r];
        if (MODE == 0) {
          int b = row >> 11, s = row & 2047, h = col >> 7, hd = col & 127;
          ((unsigned short*)Cout)[(((size_t)b * 16 + h) * 2048 + s) * 128 + hd] =
              f2bf(v * scale);
        } else if (MODE == 2) {
          int b = row >> 11, s = row & 2047, h = col >> 7, hd = col & 127;
          ((unsigned short*)Cout)[(((size_t)b * 16 + h) * 128 + hd) * 2048 + s] =
              f2bf(v);
        } else {
          ((float*)Cout)[(size_t)row * 2048 + col] = v;
        }
      }
}

// ---------------------------------------------------------------------------
// Flash attention, causal, swapped-operand, 32x32x16 MFMA.
// Q,K: [B,H,S,HD] bf16 (Q prescaled by SMSCALE*L2E). Vt: [B,H,HD,S] bf16.
// O: [B,S,D] bf16. 8 waves x 32 q-rows, KVBLK=64, dbuf LDS, XOR swizzle.
// ---------------------------------------------------------------------------
__global__ __launch_bounds__(512) void k_attn(const unsigned short* __restrict__ Q,
                                              const unsigned short* __restrict__ K,
                                              const unsigned short* __restrict__ Vt,
                                              unsigned short* __restrict__ O) {
  __shared__ __align__(16) unsigned char lds[65536];   // 2 x (16K K + 16K V)
  const int tid = threadIdx.x;
  const int ln = tid & 63, w = tid >> 6;
  const int l31 = ln & 31, hi = ln >> 5;
  const int rk = l31 & 15;
  const int bx = blockIdx.x;
  // balanced heavy/light pairing: CU c gets qb 7-g and g -> uniform 36 tiles
  const int gqb = bx >> 6;
  const int qb = (bx < 256) ? (7 - gqb) : (gqb - 4);
  const int bh = bx & 63;
  const int q0 = qb * 256;
  const size_t base = (size_t)bh * 2048 * 128;
  const unsigned short* Qb = Q + base;
  const unsigned short* Kb = K + base;
  const unsigned short* Vb = Vt + base;

  const int qw0 = q0 + w * 32;
  const int qg = qw0 + l31;

  // Q fragments (B-operand: col q = lane&31, d = dc*16 + hi*8 + j)
  bfrag qf[8];
#pragma unroll
  for (int dc = 0; dc < 8; ++dc)
    qf[dc] = *(const bfrag*)(Qb + (size_t)qg * 128 + dc * 16 + hi * 8);

  f32x16 o[4] = {};            // O^T acc: [d = db*32 + pat(r,hi)][q = lane&31]
  float m_r = NEGBIG, l_r = 0.f;

  const int nt = q0 / 64 + 4;

  // stage K tile [64][16ch] and V^T tile [64row'][16ch], XOR-16 swizzled
  auto stage = [&](int buf, int k0) {
    unsigned char* Kt = lds + buf * 32768;
    unsigned char* Vl = Kt + 16384;
#pragma unroll
    for (int i = 0; i < 2; ++i) {
      int cid = i * 512 + tid;
      int row = cid >> 4, p = cid & 15, sc = p ^ (row & 15);
      gload16(Kb + (size_t)(k0 + row) * 128 + sc * 8, Kt + cid * 16);
    }
#pragma unroll
    for (int i = 0; i < 2; ++i) {
      int cid = i * 512 + tid;
      int row = cid >> 4, p = cid & 15, sc = p ^ (row & 15);
      int d = (sc >> 3) * 64 + row;
      gload16(Vb + (size_t)d * 2048 + k0 + (sc & 7) * 8, Vl + cid * 16);
    }
  };

  stage(0, 0);
  DRAIN_VM;
  __syncthreads();
  int buf = 0;

  for (int t = 0; t < nt; ++t) {
    const int k0 = t * 64;
    if (t + 1 < nt) stage(buf ^ 1, k0 + 64);   // prefetch under compute

    if (k0 <= qw0 + 31) {                      // wave-uniform causal skip
      const unsigned char* Kt = lds + buf * 32768;
      const unsigned char* Vl = Kt + 16384;

      // ---- S^T = K * Q^T  (k rows, q cols)
      f32x16 s0 = {}, s1 = {};
#pragma unroll
      for (int dc = 0; dc < 8; ++dc) {
        int c = dc * 2 + hi;
        bfrag ka = *(const bfrag*)(Kt + (size_t)l31 * 256 + ((c ^ rk) << 4));
        bfrag kb2 = *(const bfrag*)(Kt + (size_t)(32 + l31) * 256 + ((c ^ rk) << 4));
        s0 = __builtin_amdgcn_mfma_f32_32x32x16_bf16(ka, qf[dc], s0, 0, 0, 0);
        s1 = __builtin_amdgcn_mfma_f32_32x32x16_bf16(kb2, qf[dc], s1, 0, 0, 0);
      }

      // ---- causal mask (diagonal tiles only)
      if (k0 + 63 > qw0) {
#pragma unroll
        for (int r = 0; r < 16; ++r) {
          int ko = (r & 3) + 8 * (r >> 2) + 4 * hi;
          if (k0 + ko > qg) s0[r] = NEGBIG;
          if (k0 + 32 + ko > qg) s1[r] = NEGBIG;
        }
      }

      // ---- row max
      float pmax = s0[0];
#pragma unroll
      for (int r = 1; r < 16; ++r) pmax = fmaxf(pmax, s0[r]);
#pragma unroll
      for (int r = 0; r < 16; ++r) pmax = fmaxf(pmax, s1[r]);
      pmax = fmaxf(pmax, __shfl_xor(pmax, 32));

      // ---- defer-max rescale (T13), log2 domain
      if (!__all(pmax - m_r <= 12.f)) {
        float mn = fmaxf(m_r, pmax);
        float al = EXP2(m_r - mn);
        l_r *= al;
#pragma unroll
        for (int db = 0; db < 4; ++db)
#pragma unroll
          for (int r = 0; r < 16; ++r) o[db][r] *= al;
        m_r = mn;
      }

      // ---- exp2 + pack to bf16 quads
      unsigned qd0[8], qd1[8];
      float rs = 0.f;
#pragma unroll
      for (int s = 0; s < 4; ++s) {
        float p0 = EXP2(s0[4 * s + 0] - m_r), p1 = EXP2(s0[4 * s + 1] - m_r);
        float p2 = EXP2(s0[4 * s + 2] - m_r), p3 = EXP2(s0[4 * s + 3] - m_r);
        rs += (p0 + p1) + (p2 + p3);
        qd0[2 * s] = (unsigned)f2bf(p0) | ((unsigned)f2bf(p1) << 16);
        qd0[2 * s + 1] = (unsigned)f2bf(p2) | ((unsigned)f2bf(p3) << 16);
      }
#pragma unroll
      for (int s = 0; s < 4; ++s) {
        float p0 = EXP2(s1[4 * s + 0] - m_r), p1 = EXP2(s1[4 * s + 1] - m_r);
        float p2 = EXP2(s1[4 * s + 2] - m_r), p3 = EXP2(s1[4 * s + 3] - m_r);
        rs += (p0 + p1) + (p2 + p3);
        qd1[2 * s] = (unsigned)f2bf(p0) | ((unsigned)f2bf(p1) << 16);
        qd1[2 * s + 1] = (unsigned)f2bf(p2) | ((unsigned)f2bf(p3) << 16);
      }
      rs += __shfl_xor(rs, 32);
      l_r += rs;

      // ---- O^T += V^T * P^T
#define PVSTEP(QD, B0, KC)                                                    \
  do {                                                                        \
    unsigned e0 = QD[B0], e1 = QD[B0 + 1], x0 = QD[B0 + 2], x1 = QD[B0 + 3];  \
    unsigned kp0 = hi ? x0 : e0, kp1 = hi ? x1 : e1;                          \
    unsigned sd0 = hi ? e0 : x0, sd1 = hi ? e1 : x1;                          \
    unsigned rc0 = (unsigned)__shfl_xor((int)sd0, 32);                        \
    unsigned rc1 = (unsigned)__shfl_xor((int)sd1, 32);                        \
    unsigned pw[4];                                                           \
    pw[0] = hi ? rc0 : kp0; pw[1] = hi ? rc1 : kp1;                           \
    pw[2] = hi ? kp0 : rc0; pw[3] = hi ? kp1 : rc1;                           \
    bfrag pf = *(bfrag*)pw;                                                   \
    _Pragma("unroll")                                                         \
    for (int db = 0; db < 4; ++db) {                                          \
      int c = (db >> 1) * 8 + KC * 2 + hi;                                    \
      bfrag vf = *(const bfrag*)(Vl + (size_t)((db & 1) * 32 + l31) * 256 +   \
                                 ((c ^ rk) << 4));                            \
      o[db] = __builtin_amdgcn_mfma_f32_32x32x16_bf16(vf, pf, o[db], 0, 0, 0);\
    }                                                                         \
  } while (0)

      PVSTEP(qd0, 0, 0);
      PVSTEP(qd0, 4, 1);
      PVSTEP(qd1, 0, 2);
      PVSTEP(qd1, 4, 3);
#undef PVSTEP
    }
    DRAIN_VM;
    __syncthreads();
    buf ^= 1;
  }

  // ---- epilogue: normalize, transpose O^T -> O via LDS (2 phases, 4 waves)
  float invl = 1.0f / l_r;
  const int b_ = bh >> 4, h_ = bh & 15;
#pragma unroll
  for (int ph = 0; ph < 2; ++ph) {
    if ((w >> 2) == ph) {
      unsigned char* ep = lds + (w & 3) * 8704;   // [32 q][136 d] bf16
#pragma unroll
      for (int db = 0; db < 4; ++db)
#pragma unroll
        for (int s = 0; s < 4; ++s) {
          int d0 = db * 32 + 8 * s + 4 * hi;
          float v0 = o[db][4 * s] * invl, v1 = o[db][4 * s + 1] * invl;
          float v2 = o[db][4 * s + 2] * invl, v3 = o[db][4 * s + 3] * invl;
          uint2 pw;
          pw.x = (unsigned)f2bf(v0) | ((unsigned)f2bf(v1) << 16);
          pw.y = (unsigned)f2bf(v2) | ((unsigned)f2bf(v3) << 16);
          *(uint2*)(ep + l31 * 272 + d0 * 2) = pw;
        }
    }
    __syncthreads();
    if ((w >> 2) == ph) {
      const unsigned char* ep = lds + (w & 3) * 8704;
#pragma unroll
      for (int i = 0; i < 8; ++i) {
        int cid = i * 64 + ln;
        int q = cid >> 4, ch = cid & 15;
        uint4 val = *(const uint4*)(ep + q * 272 + ch * 16);
        *(uint4*)(O + ((size_t)(b_ * 2048 + q0 + w * 32 + q)) * 2048 +
                  h_ * 128 + ch * 8) = val;
      }
    }
    __syncthreads();
  }
}

// ---------------------------------------------------------------------------
extern "C" void kernel_launch(void* const* d_in, const int* in_sizes, int n_in,
                              void* d_out, int out_size, void* d_ws, size_t ws_size,
                              hipStream_t stream) {
  (void)in_sizes; (void)n_in; (void)out_size; (void)ws_size;
  const float* x  = (const float*)d_in[0];
  /* d_in[1] = mask: causal tril, handled analytically */
  const float* Wq = (const float*)d_in[2];
  const float* Aq = (const float*)d_in[3];
  const float* Bq = (const float*)d_in[4];
  const float* Wk = (const float*)d_in[5];
  const float* Ak = (const float*)d_in[6];
  const float* Bk = (const float*)d_in[7];
  const float* Wv = (const float*)d_in[8];
  const float* Av = (const float*)d_in[9];
  const float* Bv = (const float*)d_in[10];
  const float* Wo = (const float*)d_in[11];
  const float* Ao = (const float*)d_in[12];
  const float* Bo = (const float*)d_in[13];

  char* ws = (char*)d_ws;
  unsigned short* xbf = (unsigned short*)ws;                       // 32 MiB
  unsigned short* Wqe = (unsigned short*)(ws + (size_t)33554432);  // 4 x 8 MiB
  unsigned short* Wke = Wqe + 2048 * 2048;
  unsigned short* Wve = Wke + 2048 * 2048;
  unsigned short* Woe = Wve + 2048 * 2048;
  unsigned short* Qb  = (unsigned short*)(ws + (size_t)33554432 + 4u * 8388608u);
  unsigned short* Kb  = Qb + 16777216;                             // 3 x 32 MiB
  unsigned short* Vtb = Kb + 16777216;                             // V^T
  unsigned short* AO  = xbf;   // reuse x_bf16 buffer for attention output

  k_fold<<<2048, 256, 0, stream>>>(Wq, Aq, Bq, Wqe);
  k_fold<<<2048, 256, 0, stream>>>(Wk, Ak, Bk, Wke);
  k_fold<<<2048, 256, 0, stream>>>(Wv, Av, Bv, Wve);
  k_fold<<<2048, 256, 0, stream>>>(Wo, Ao, Bo, Woe);
  k_cvt<<<8192, 256, 0, stream>>>(x, xbf);

  k_gemm2<0><<<256, 512, 0, stream>>>(xbf, Wqe, Qb, SMSCALE * L2E);  // Q prescaled
  k_gemm2<0><<<256, 512, 0, stream>>>(xbf, Wke, Kb, 1.0f);
  k_gemm2<2><<<256, 512, 0, stream>>>(xbf, Wve, Vtb, 1.0f);          // V transposed

  k_attn<<<512, 512, 0, stream>>>(Qb, Kb, Vtb, AO);

  k_gemm2<1><<<256, 512, 0, stream>>>(AO, Woe, d_out, 1.0f);
}

// Round 5
// 411.233 us; speedup vs baseline: 2.2878x; 1.0268x over previous
//
#include <hip/hip_runtime.h>
#include <hip/hip_bf16.h>
#include <stdint.h>

// ---------------------------------------------------------------------------
// LoRA attention, fully bf16-MFMA path.
//   y = x@(W + B@A)^T for q,k,v ; flash-attn causal (swapped-operand) ;
//   o-proj to fp32.
// Shapes: B=4 S=2048 D=2048 H=16 HD=128 R=16. M = B*S = 8192.
// ---------------------------------------------------------------------------

#define L2E 1.4426950408889634f
#define SMSCALE 0.08838834764831845f
#define NEGBIG -3.0e38f

typedef __attribute__((ext_vector_type(4))) float f32x4;
typedef __attribute__((ext_vector_type(16))) float f32x16;
typedef __attribute__((ext_vector_type(8))) __bf16 bfrag;   // 8 bf16 = 4 VGPR

#if __has_builtin(__builtin_amdgcn_exp2f)
#define EXP2 __builtin_amdgcn_exp2f
#else
#define EXP2 exp2f
#endif

// Explicit LDS-DMA drain (k_attn): the epilogue reuses the prefetch LDS
// region, so a late-landing global_load_lds would stomp it.
#define DRAIN_VM                                      \
  do {                                                \
    asm volatile("s_waitcnt vmcnt(0)" ::: "memory");  \
    __builtin_amdgcn_sched_barrier(0);                \
  } while (0)

static __device__ __forceinline__ unsigned short f2bf(float f) {
  union { float f; unsigned u; } v; v.f = f;
  unsigned r = v.u + 0x7FFFu + ((v.u >> 16) & 1u);   // RNE
  return (unsigned short)(r >> 16);
}

static __device__ __forceinline__ void gload16(const void* g, void* l) {
  __builtin_amdgcn_global_load_lds(
      (const __attribute__((address_space(1))) void*)g,
      (__attribute__((address_space(3))) void*)l, 16, 0, 0);
}

// ---------------------------------------------------------------------------
// Weff[n][k] = W[n][k] + sum_r Bm[n][r] * A[r][k]   -> bf16
// ---------------------------------------------------------------------------
__global__ __launch_bounds__(256) void k_fold(const float* __restrict__ W,
                                              const float* __restrict__ A,
                                              const float* __restrict__ Bm,
                                              unsigned short* __restrict__ out) {
  const int n = blockIdx.x;
  const int k0 = threadIdx.x * 8;
  const float* wr = W + (size_t)n * 2048 + k0;
  float acc[8];
#pragma unroll
  for (int j = 0; j < 8; ++j) acc[j] = wr[j];
#pragma unroll 4
  for (int r = 0; r < 16; ++r) {
    float b = Bm[n * 16 + r];
    const float* ar = A + (size_t)r * 2048 + k0;
#pragma unroll
    for (int j = 0; j < 8; ++j) acc[j] = fmaf(b, ar[j], acc[j]);
  }
  unsigned short o[8];
#pragma unroll
  for (int j = 0; j < 8; ++j) o[j] = f2bf(acc[j]);
  *(uint4*)(out + (size_t)n * 2048 + k0) = *(const uint4*)o;
}

// ---------------------------------------------------------------------------
__global__ __launch_bounds__(256) void k_cvt(const float* __restrict__ in,
                                             unsigned short* __restrict__ out) {
  const size_t i = ((size_t)blockIdx.x * 256 + threadIdx.x) * 8;
  unsigned short o[8];
#pragma unroll
  for (int j = 0; j < 8; ++j) o[j] = f2bf(in[i + j]);
  *(uint4*)(out + i) = *(const uint4*)o;
}

// ---------------------------------------------------------------------------
// GEMM2: 256x256 tile, BK=64, 8 waves (2Mx4N), phase-interleaved counted-vmcnt
// pipeline, 128 KiB LDS.   C[m][n] = sum_k A[m][k] * Bw[n][k]
// LDS per operand: [2 buf][2 K-half][256 rows][32 k] bf16; within a row (64B,
// 4 chunks of 16B) chunk c sits at position c ^ ((row>>1)&3)  (2-way banks).
// Deep schedule (1.5 tiles in flight, 4-phase slack, 2-barrier overwrite
// margin). Issues:  T.p1 -> (T+1).h1   |   T.p3 -> (T+2).h0
// Waits (before barrier):  T.p1: vmcnt(8) retires T.h1   (flight 4 phases)
//                          T.p3: vmcnt(8) retires (T+1).h0 (flight 4 phases)
// FIFO ledger (steady state, 4 loads/group):
//   outstanding after T.p1 wait = {(T+1).h0,(T+1).h1} = 8
//   T.p3 issue -> 12, wait 8 retires (T+1).h0  -> invariant holds.
// Overwrite margins: p1-stage targets region last read (T-1).p2/p3 (2 barriers
// back); p3-stage targets region last read T.p0/p1 (2 barriers back).
// Epilogue: T=31.p1 and T>=30.p3 use vmcnt(0) (tail drain, cheap).
// MODE 0: bf16 -> [B,H,S,HD] scaled. MODE 1: fp32 flat. MODE 2: bf16 [B,H,HD,S].
// ---------------------------------------------------------------------------
template <int MODE>
__global__ __launch_bounds__(512, 2) void k_gemm2(const unsigned short* __restrict__ A,
                                                  const unsigned short* __restrict__ Bw,
                                                  void* __restrict__ Cout, float scale) {
  __shared__ __align__(16) unsigned char lds[131072];
  unsigned char* Al = lds;            // A: 2 x 32 KB
  unsigned char* Bl = lds + 65536;    // B: 2 x 32 KB
  const int tid = threadIdx.x, ln = tid & 63;
  const int w = tid >> 6, g = ln >> 4, cc = ln & 15;
  const int wm = w >> 2, wn = w & 3;
  const int bid = blockIdx.x;
  const int wg = (bid & 7) * 32 + (bid >> 3);   // bijective XCD swizzle (256 wgs)
  const int m0 = (wg >> 3) * 256, n0 = (wg & 7) * 256;

  // per-thread staging constants: cid = i*512+tid -> row, chunk pos
  int soff[2], sdst[2];
#pragma unroll
  for (int i = 0; i < 2; ++i) {
    int cid = i * 512 + tid, r = cid >> 2, p = cid & 3;
    int sc = p ^ ((r >> 1) & 3);
    soff[i] = r * 2048 + sc * 8;      // + base_row*2048 + kt + h*32
    sdst[i] = cid * 16;               // + buf*32768 + h*16384
  }
  // per-thread ds_read offsets
  int aro[8], bro[4];
#pragma unroll
  for (int fm = 0; fm < 8; ++fm) {
    int r = wm * 128 + fm * 16 + cc;
    aro[fm] = r * 64 + ((g ^ ((r >> 1) & 3)) << 4);
  }
#pragma unroll
  for (int fn = 0; fn < 4; ++fn) {
    int r = wn * 64 + fn * 16 + cc;
    bro[fn] = r * 64 + ((g ^ ((r >> 1) & 3)) << 4);
  }

#define STAGE_A(b, kt, h)                                                   \
  do {                                                                      \
    _Pragma("unroll")                                                       \
    for (int i = 0; i < 2; ++i)                                             \
      gload16(A + (size_t)m0 * 2048 + soff[i] + (kt) + (h) * 32,            \
              Al + (b) * 32768 + (h) * 16384 + sdst[i]);                    \
  } while (0)
#define STAGE_B(b, kt, h)                                                   \
  do {                                                                      \
    _Pragma("unroll")                                                       \
    for (int i = 0; i < 2; ++i)                                             \
      gload16(Bw + (size_t)n0 * 2048 + soff[i] + (kt) + (h) * 32,           \
              Bl + (b) * 32768 + (h) * 16384 + sdst[i]);                    \
  } while (0)

  f32x4 acc[8][4] = {};

  // prologue: 0.h0, 0.h1, 1.h0 in flight; land 0.h0 (oldest 4)
  STAGE_A(0, 0, 0); STAGE_B(0, 0, 0);
  STAGE_A(0, 0, 1); STAGE_B(0, 0, 1);
  STAGE_A(1, 64, 0); STAGE_B(1, 64, 0);
  asm volatile("s_waitcnt vmcnt(8)" ::: "memory");
  __builtin_amdgcn_s_barrier();
  __builtin_amdgcn_sched_barrier(0);

  for (int T = 0; T < 32; ++T) {
    const int buf = T & 1;
    const unsigned char* Ab = Al + buf * 32768;
    const unsigned char* Bb = Bl + buf * 32768;
#pragma unroll
    for (int ks = 0; ks < 2; ++ks) {
      bfrag af[8], bf[4];
      // ---- phase p0/p2 : bulk reads (A frags + B n-frags 0,1), MFMA fn01
#pragma unroll
      for (int fm = 0; fm < 8; ++fm)
        af[fm] = *(const bfrag*)(Ab + ks * 16384 + aro[fm]);
#pragma unroll
      for (int j = 0; j < 2; ++j)
        bf[j] = *(const bfrag*)(Bb + ks * 16384 + bro[j]);
      __builtin_amdgcn_sched_barrier(0);
      __builtin_amdgcn_s_barrier();
      __builtin_amdgcn_sched_barrier(0);
      __builtin_amdgcn_s_setprio(1);
#pragma unroll
      for (int fm = 0; fm < 8; ++fm)
#pragma unroll
        for (int j = 0; j < 2; ++j)
          acc[fm][j] = __builtin_amdgcn_mfma_f32_16x16x32_bf16(af[fm], bf[j],
                                                               acc[fm][j], 0, 0, 0);
      __builtin_amdgcn_s_setprio(0);
      __builtin_amdgcn_sched_barrier(0);
      // ---- phase p1/p3 : tail reads (B n-frags 2,3), stage, wait, MFMA fn23
#pragma unroll
      for (int j = 0; j < 2; ++j)
        bf[2 + j] = *(const bfrag*)(Bb + ks * 16384 + bro[2 + j]);
      if (ks == 0) {
        if (T + 1 < 32) {               // (T+1).h1 -> buf^1
          STAGE_A(buf ^ 1, (T + 1) * 64, 1);
          STAGE_B(buf ^ 1, (T + 1) * 64, 1);
        }
        __builtin_amdgcn_sched_barrier(0);
        if (T < 31) asm volatile("s_waitcnt vmcnt(8)" ::: "memory");
        else        asm volatile("s_waitcnt vmcnt(0)" ::: "memory");
      } else {
        if (T + 2 < 32) {               // (T+2).h0 -> buf
          STAGE_A(buf, (T + 2) * 64, 0);
          STAGE_B(buf, (T + 2) * 64, 0);
        }
        __builtin_amdgcn_sched_barrier(0);
        if (T < 30) asm volatile("s_waitcnt vmcnt(8)" ::: "memory");
        else        asm volatile("s_waitcnt vmcnt(0)" ::: "memory");
      }
      __builtin_amdgcn_s_barrier();
      __builtin_amdgcn_sched_barrier(0);
      __builtin_amdgcn_s_setprio(1);
#pragma unroll
      for (int fm = 0; fm < 8; ++fm)
#pragma unroll
        for (int j = 0; j < 2; ++j)
          acc[fm][2 + j] = __builtin_amdgcn_mfma_f32_16x16x32_bf16(af[fm], bf[2 + j],
                                                                   acc[fm][2 + j], 0, 0, 0);
      __builtin_amdgcn_s_setprio(0);
      __builtin_amdgcn_sched_barrier(0);
    }
  }
#undef STAGE_A
#undef STAGE_B

  // ---- epilogue: direct global stores from registers (no LDS use)
#pragma unroll
  for (int fm = 0; fm < 8; ++fm)
#pragma unroll
    for (int fn = 0; fn < 4; ++fn)
#pragma unroll
      for (int r = 0; r < 4; ++r) {
        int row = m0 + wm * 128 + fm * 16 + g * 4 + r;   // m = b*2048+s
        int col = n0 + wn * 64 + fn * 16 + cc;           // n = h*128+hd
        float v = acc[fm][fn][r];
        if (MODE == 0) {
          int b = row >> 11, s = row & 2047, h = col >> 7, hd = col & 127;
          ((unsigned short*)Cout)[(((size_t)b * 16 + h) * 2048 + s) * 128 + hd] =
              f2bf(v * scale);
        } else if (MODE == 2) {
          int b = row >> 11, s = row & 2047, h = col >> 7, hd = col & 127;
          ((unsigned short*)Cout)[(((size_t)b * 16 + h) * 128 + hd) * 2048 + s] =
              f2bf(v);
        } else {
          ((float*)Cout)[(size_t)row * 2048 + col] = v;
        }
      }
}

// ---------------------------------------------------------------------------
// Flash attention, causal, swapped-operand, 32x32x16 MFMA.
// Q,K: [B,H,S,HD] bf16 (Q prescaled by SMSCALE*L2E). Vt: [B,H,HD,S] bf16.
// O: [B,S,D] bf16. 8 waves x 32 q-rows, KVBLK=64, dbuf LDS, XOR swizzle.
// Dispatch: heavy-first qb = 7-(bx>>6)  (empirically best, round-3 vs 4 A/B).
// ---------------------------------------------------------------------------
__global__ __launch_bounds__(512) void k_attn(const unsigned short* __restrict__ Q,
                                              const unsigned short* __restrict__ K,
                                              const unsigned short* __restrict__ Vt,
                                              unsigned short* __restrict__ O) {
  __shared__ __align__(16) unsigned char lds[65536];   // 2 x (16K K + 16K V)
  const int tid = threadIdx.x;
  const int ln = tid & 63, w = tid >> 6;
  const int l31 = ln & 31, hi = ln >> 5;
  const int rk = l31 & 15;
  const int bx = blockIdx.x;
  const int qb = 7 - (bx >> 6);          // heavy-first dispatch order
  const int bh = bx & 63;
  const int q0 = qb * 256;
  const size_t base = (size_t)bh * 2048 * 128;
  const unsigned short* Qb = Q + base;
  const unsigned short* Kb = K + base;
  const unsigned short* Vb = Vt + base;

  const int qw0 = q0 + w * 32;
  const int qg = qw0 + l31;

  // Q fragments (B-operand: col q = lane&31, d = dc*16 + hi*8 + j)
  bfrag qf[8];
#pragma unroll
  for (int dc = 0; dc < 8; ++dc)
    qf[dc] = *(const bfrag*)(Qb + (size_t)qg * 128 + dc * 16 + hi * 8);

  f32x16 o[4] = {};            // O^T acc: [d = db*32 + pat(r,hi)][q = lane&31]
  float m_r = NEGBIG, l_r = 0.f;

  const int nt = q0 / 64 + 4;

  // stage K tile [64][16ch] and V^T tile [64row'][16ch], XOR-16 swizzled
  auto stage = [&](int buf, int k0) {
    unsigned char* Kt = lds + buf * 32768;
    unsigned char* Vl = Kt + 16384;
#pragma unroll
    for (int i = 0; i < 2; ++i) {
      int cid = i * 512 + tid;
      int row = cid >> 4, p = cid & 15, sc = p ^ (row & 15);
      gload16(Kb + (size_t)(k0 + row) * 128 + sc * 8, Kt + cid * 16);
    }
#pragma unroll
    for (int i = 0; i < 2; ++i) {
      int cid = i * 512 + tid;
      int row = cid >> 4, p = cid & 15, sc = p ^ (row & 15);
      int d = (sc >> 3) * 64 + row;
      gload16(Vb + (size_t)d * 2048 + k0 + (sc & 7) * 8, Vl + cid * 16);
    }
  };

  stage(0, 0);
  DRAIN_VM;
  __syncthreads();
  int buf = 0;

  for (int t = 0; t < nt; ++t) {
    const int k0 = t * 64;
    if (t + 1 < nt) stage(buf ^ 1, k0 + 64);   // prefetch under compute

    if (k0 <= qw0 + 31) {                      // wave-uniform causal skip
      const unsigned char* Kt = lds + buf * 32768;
      const unsigned char* Vl = Kt + 16384;

      // ---- S^T = K * Q^T  (k rows, q cols)
      f32x16 s0 = {}, s1 = {};
#pragma unroll
      for (int dc = 0; dc < 8; ++dc) {
        int c = dc * 2 + hi;
        bfrag ka = *(const bfrag*)(Kt + (size_t)l31 * 256 + ((c ^ rk) << 4));
        bfrag kb2 = *(const bfrag*)(Kt + (size_t)(32 + l31) * 256 + ((c ^ rk) << 4));
        s0 = __builtin_amdgcn_mfma_f32_32x32x16_bf16(ka, qf[dc], s0, 0, 0, 0);
        s1 = __builtin_amdgcn_mfma_f32_32x32x16_bf16(kb2, qf[dc], s1, 0, 0, 0);
      }

      // ---- causal mask (diagonal tiles only)
      if (k0 + 63 > qw0) {
#pragma unroll
        for (int r = 0; r < 16; ++r) {
          int ko = (r & 3) + 8 * (r >> 2) + 4 * hi;
          if (k0 + ko > qg) s0[r] = NEGBIG;
          if (k0 + 32 + ko > qg) s1[r] = NEGBIG;
        }
      }

      // ---- row max
      float pmax = s0[0];
#pragma unroll
      for (int r = 1; r < 16; ++r) pmax = fmaxf(pmax, s0[r]);
#pragma unroll
      for (int r = 0; r < 16; ++r) pmax = fmaxf(pmax, s1[r]);
      pmax = fmaxf(pmax, __shfl_xor(pmax, 32));

      // ---- defer-max rescale (T13), log2 domain
      if (!__all(pmax - m_r <= 12.f)) {
        float mn = fmaxf(m_r, pmax);
        float al = EXP2(m_r - mn);
        l_r *= al;
#pragma unroll
        for (int db = 0; db < 4; ++db)
#pragma unroll
          for (int r = 0; r < 16; ++r) o[db][r] *= al;
        m_r = mn;
      }

      // ---- exp2 + pack to bf16 quads
      unsigned qd0[8], qd1[8];
      float rs = 0.f;
#pragma unroll
      for (int s = 0; s < 4; ++s) {
        float p0 = EXP2(s0[4 * s + 0] - m_r), p1 = EXP2(s0[4 * s + 1] - m_r);
        float p2 = EXP2(s0[4 * s + 2] - m_r), p3 = EXP2(s0[4 * s + 3] - m_r);
        rs += (p0 + p1) + (p2 + p3);
        qd0[2 * s] = (unsigned)f2bf(p0) | ((unsigned)f2bf(p1) << 16);
        qd0[2 * s + 1] = (unsigned)f2bf(p2) | ((unsigned)f2bf(p3) << 16);
      }
#pragma unroll
      for (int s = 0; s < 4; ++s) {
        float p0 = EXP2(s1[4 * s + 0] - m_r), p1 = EXP2(s1[4 * s + 1] - m_r);
        float p2 = EXP2(s1[4 * s + 2] - m_r), p3 = EXP2(s1[4 * s + 3] - m_r);
        rs += (p0 + p1) + (p2 + p3);
        qd1[2 * s] = (unsigned)f2bf(p0) | ((unsigned)f2bf(p1) << 16);
        qd1[2 * s + 1] = (unsigned)f2bf(p2) | ((unsigned)f2bf(p3) << 16);
      }
      rs += __shfl_xor(rs, 32);
      l_r += rs;

      // ---- O^T += V^T * P^T
#define PVSTEP(QD, B0, KC)                                                    \
  do {                                                                        \
    unsigned e0 = QD[B0], e1 = QD[B0 + 1], x0 = QD[B0 + 2], x1 = QD[B0 + 3];  \
    unsigned kp0 = hi ? x0 : e0, kp1 = hi ? x1 : e1;                          \
    unsigned sd0 = hi ? e0 : x0, sd1 = hi ? e1 : x1;                          \
    unsigned rc0 = (unsigned)__shfl_xor((int)sd0, 32);                        \
    unsigned rc1 = (unsigned)__shfl_xor((int)sd1, 32);                        \
    unsigned pw[4];                                                           \
    pw[0] = hi ? rc0 : kp0; pw[1] = hi ? rc1 : kp1;                           \
    pw[2] = hi ? kp0 : rc0; pw[3] = hi ? kp1 : rc1;                           \
    bfrag pf = *(bfrag*)pw;                                                   \
    _Pragma("unroll")                                                         \
    for (int db = 0; db < 4; ++db) {                                          \
      int c = (db >> 1) * 8 + KC * 2 + hi;                                    \
      bfrag vf = *(const bfrag*)(Vl + (size_t)((db & 1) * 32 + l31) * 256 +   \
                                 ((c ^ rk) << 4));                            \
      o[db] = __builtin_amdgcn_mfma_f32_32x32x16_bf16(vf, pf, o[db], 0, 0, 0);\
    }                                                                         \
  } while (0)

      PVSTEP(qd0, 0, 0);
      PVSTEP(qd0, 4, 1);
      PVSTEP(qd1, 0, 2);
      PVSTEP(qd1, 4, 3);
#undef PVSTEP
    }
    DRAIN_VM;
    __syncthreads();
    buf ^= 1;
  }

  // ---- epilogue: normalize, transpose O^T -> O via LDS (2 phases, 4 waves)
  float invl = 1.0f / l_r;
  const int b_ = bh >> 4, h_ = bh & 15;
#pragma unroll
  for (int ph = 0; ph < 2; ++ph) {
    if ((w >> 2) == ph) {
      unsigned char* ep = lds + (w & 3) * 8704;   // [32 q][136 d] bf16
#pragma unroll
      for (int db = 0; db < 4; ++db)
#pragma unroll
        for (int s = 0; s < 4; ++s) {
          int d0 = db * 32 + 8 * s + 4 * hi;
          float v0 = o[db][4 * s] * invl, v1 = o[db][4 * s + 1] * invl;
          float v2 = o[db][4 * s + 2] * invl, v3 = o[db][4 * s + 3] * invl;
          uint2 pw;
          pw.x = (unsigned)f2bf(v0) | ((unsigned)f2bf(v1) << 16);
          pw.y = (unsigned)f2bf(v2) | ((unsigned)f2bf(v3) << 16);
          *(uint2*)(ep + l31 * 272 + d0 * 2) = pw;
        }
    }
    __syncthreads();
    if ((w >> 2) == ph) {
      const unsigned char* ep = lds + (w & 3) * 8704;
#pragma unroll
      for (int i = 0; i < 8; ++i) {
        int cid = i * 64 + ln;
        int q = cid >> 4, ch = cid & 15;
        uint4 val = *(const uint4*)(ep + q * 272 + ch * 16);
        *(uint4*)(O + ((size_t)(b_ * 2048 + q0 + w * 32 + q)) * 2048 +
                  h_ * 128 + ch * 8) = val;
      }
    }
    __syncthreads();
  }
}

// ---------------------------------------------------------------------------
extern "C" void kernel_launch(void* const* d_in, const int* in_sizes, int n_in,
                              void* d_out, int out_size, void* d_ws, size_t ws_size,
                              hipStream_t stream) {
  (void)in_sizes; (void)n_in; (void)out_size; (void)ws_size;
  const float* x  = (const float*)d_in[0];
  /* d_in[1] = mask: causal tril, handled analytically */
  const float* Wq = (const float*)d_in[2];
  const float* Aq = (const float*)d_in[3];
  const float* Bq = (const float*)d_in[4];
  const float* Wk = (const float*)d_in[5];
  const float* Ak = (const float*)d_in[6];
  const float* Bk = (const float*)d_in[7];
  const float* Wv = (const float*)d_in[8];
  const float* Av = (const float*)d_in[9];
  const float* Bv = (const float*)d_in[10];
  const float* Wo = (const float*)d_in[11];
  const float* Ao = (const float*)d_in[12];
  const float* Bo = (const float*)d_in[13];

  char* ws = (char*)d_ws;
  unsigned short* xbf = (unsigned short*)ws;                       // 32 MiB
  unsigned short* Wqe = (unsigned short*)(ws + (size_t)33554432);  // 4 x 8 MiB
  unsigned short* Wke = Wqe + 2048 * 2048;
  unsigned short* Wve = Wke + 2048 * 2048;
  unsigned short* Woe = Wve + 2048 * 2048;
  unsigned short* Qb  = (unsigned short*)(ws + (size_t)33554432 + 4u * 8388608u);
  unsigned short* Kb  = Qb + 16777216;                             // 3 x 32 MiB
  unsigned short* Vtb = Kb + 16777216;                             // V^T
  unsigned short* AO  = xbf;   // reuse x_bf16 buffer for attention output

  k_fold<<<2048, 256, 0, stream>>>(Wq, Aq, Bq, Wqe);
  k_fold<<<2048, 256, 0, stream>>>(Wk, Ak, Bk, Wke);
  k_fold<<<2048, 256, 0, stream>>>(Wv, Av, Bv, Wve);
  k_fold<<<2048, 256, 0, stream>>>(Wo, Ao, Bo, Woe);
  k_cvt<<<8192, 256, 0, stream>>>(x, xbf);

  k_gemm2<0><<<256, 512, 0, stream>>>(xbf, Wqe, Qb, SMSCALE * L2E);  // Q prescaled
  k_gemm2<0><<<256, 512, 0, stream>>>(xbf, Wke, Kb, 1.0f);
  k_gemm2<2><<<256, 512, 0, stream>>>(xbf, Wve, Vtb, 1.0f);          // V transposed

  k_attn<<<512, 512, 0, stream>>>(Qb, Kb, Vtb, AO);

  k_gemm2<1><<<256, 512, 0, stream>>>(AO, Woe, d_out, 1.0f);
}